// Round 1
// baseline (5797.479 us; speedup 1.0000x reference)
//
#include <hip/hip_runtime.h>
#include <cstddef>
#include <cstdint>

#define N_ROWS 65536
#define DIM    256
#define NE     8192

// output layout (float elements): x_q_ste[16777216] | loss[1] | indices[65536] | d[536870912]
#define OUT_LOSS ((size_t)16777216)
#define OUT_IDX  ((size_t)16777217)
#define OUT_D    ((size_t)16842753)

// ---------------------------------------------------------------------------
// per-row sum of squares (used for both x rows and emb rows)
__global__ __launch_bounds__(256) void sumsq_kernel(const float* __restrict__ v,
                                                    float* __restrict__ outv) {
  const int wave = threadIdx.x >> 6, lane = threadIdx.x & 63;
  const int row = blockIdx.x * 4 + wave;
  const float4 p = *(const float4*)(v + (size_t)row * DIM + 4 * lane);
  float s = p.x * p.x + p.y * p.y + p.z * p.z + p.w * p.w;
  #pragma unroll
  for (int off = 32; off; off >>= 1) s += __shfl_down(s, off);
  if (lane == 0) outv[row] = s;
}

// ---------------------------------------------------------------------------
// main fused kernel: exact fp32 GEMM tile (128 rows x 128 codes), writes d,
// per-row argmin with numpy-compatible tie-break via packed u64 atomicMin.
__global__ __launch_bounds__(256, 2) void vq_main(
    const float* __restrict__ x, const float* __restrict__ emb,
    const float* __restrict__ c_g, const float* __restrict__ e2_g,
    float* __restrict__ dD, unsigned long long* __restrict__ minkey) {
  __shared__ float lds[2 * 32 * 132];  // xs[32][132] | es[32][132]; reused as bounce[32][128]
  float* xs = lds;
  float* es = lds + 32 * 132;

  const int t = threadIdx.x;
  const int tx = t & 15, ty = t >> 4;
  const int col0 = blockIdx.x * 128;
  const int row0 = blockIdx.y * 128;

  float acc[8][8];
  #pragma unroll
  for (int i = 0; i < 8; i++)
    #pragma unroll
    for (int j = 0; j < 8; j++) acc[i][j] = 0.f;

  for (int k0 = 0; k0 < DIM; k0 += 32) {
    __syncthreads();
    // stage 128x32 chunks of x and emb, k-major in LDS (stride 132 keeps
    // b128 alignment; compute-read aliasing is 2-way = free)
    #pragma unroll
    for (int i = 0; i < 4; i++) {
      const int f = t + 256 * i;
      const int r = f >> 3, kq = f & 7;
      const float4 vx = *(const float4*)(x + (size_t)(row0 + r) * DIM + k0 + 4 * kq);
      xs[(4 * kq + 0) * 132 + r] = vx.x;
      xs[(4 * kq + 1) * 132 + r] = vx.y;
      xs[(4 * kq + 2) * 132 + r] = vx.z;
      xs[(4 * kq + 3) * 132 + r] = vx.w;
      const float4 ve = *(const float4*)(emb + (size_t)(col0 + r) * DIM + k0 + 4 * kq);
      es[(4 * kq + 0) * 132 + r] = ve.x;
      es[(4 * kq + 1) * 132 + r] = ve.y;
      es[(4 * kq + 2) * 132 + r] = ve.z;
      es[(4 * kq + 3) * 132 + r] = ve.w;
    }
    __syncthreads();
    #pragma unroll 8
    for (int kk = 0; kk < 32; kk++) {
      const float4 a0 = *(const float4*)&xs[kk * 132 + 4 * ty];
      const float4 a1 = *(const float4*)&xs[kk * 132 + 64 + 4 * ty];
      const float4 b0 = *(const float4*)&es[kk * 132 + 4 * tx];
      const float4 b1 = *(const float4*)&es[kk * 132 + 64 + 4 * tx];
      const float a[8] = {a0.x, a0.y, a0.z, a0.w, a1.x, a1.y, a1.z, a1.w};
      const float b[8] = {b0.x, b0.y, b0.z, b0.w, b1.x, b1.y, b1.z, b1.w};
      #pragma unroll
      for (int i = 0; i < 8; i++)
        #pragma unroll
        for (int j = 0; j < 8; j++)
          acc[i][j] = fmaf(a[i], b[j], acc[i][j]);
    }
  }

  // microtile -> global indices (split 4+4 layout)
  float crow[8], e2c[8];
  int rIdx[8], cIdx[8];
  #pragma unroll
  for (int i = 0; i < 8; i++) {
    rIdx[i] = row0 + ((i < 4) ? (4 * ty + i) : (64 + 4 * ty + i - 4));
    crow[i] = c_g[rIdx[i]];
  }
  #pragma unroll
  for (int j = 0; j < 8; j++) {
    cIdx[j] = col0 + ((j < 4) ? (4 * tx + j) : (64 + 4 * tx + j - 4));
    e2c[j] = e2_g[cIdx[j]];
  }

  // per-row argmin, replicating ref rounding: d = fl(fl(c + e2) - 2*dot)
  #pragma unroll
  for (int i = 0; i < 8; i++) {
    float bv = 3.4e38f;
    int bc = 0;
    #pragma unroll
    for (int j = 0; j < 8; j++) {
      const float t1 = crow[i] + e2c[j];
      const float val = t1 - 2.0f * acc[i][j];
      if (val < bv) { bv = val; bc = cIdx[j]; }  // strict < => smallest col on ties
    }
    unsigned int fb = __float_as_uint(bv);
    fb = (fb & 0x80000000u) ? ~fb : (fb | 0x80000000u);
    unsigned long long key = ((unsigned long long)fb << 32) | (unsigned int)bc;
    #pragma unroll
    for (int off = 8; off; off >>= 1) {
      unsigned long long o = __shfl_down(key, off, 16);
      if (o < key) key = o;
    }
    if (tx == 0) atomicMin(&minkey[rIdx[i]], key);
  }

  // d stores: bounce 32-row groups through LDS for coalesced scalar stores
  // (d region base is only 4B-aligned, so no vector stores)
  float* bounce = lds;
  for (int g = 0; g < 4; g++) {
    __syncthreads();
    if ((ty >> 3) == (g & 1)) {
      const int lr0 = 4 * (ty & 7);
      const int ibase = 4 * (g >> 1);
      #pragma unroll
      for (int ii = 0; ii < 4; ii++) {
        const int i = ibase + ii;
        #pragma unroll
        for (int j = 0; j < 8; j++) {
          const int lc = (j < 4) ? (4 * tx + j) : (64 + 4 * tx + j - 4);
          const float t1 = crow[i] + e2c[j];
          bounce[(lr0 + ii) * 128 + lc] = t1 - 2.0f * acc[i][j];
        }
      }
    }
    __syncthreads();
    #pragma unroll
    for (int m = 0; m < 16; m++) {
      const int e = t + 256 * m;
      const int r = e >> 7, cc = e & 127;
      dD[(size_t)(row0 + 32 * g + r) * NE + (col0 + cc)] = bounce[r * 128 + cc];
    }
  }
}

// ---------------------------------------------------------------------------
// epilogue: x_q_ste = fl(x + fl(x_q - x)), indices (as float), loss partials
__global__ __launch_bounds__(256) void vq_epilogue(
    const float* __restrict__ x, const float* __restrict__ emb,
    const unsigned long long* __restrict__ minkey,
    float* __restrict__ out, float* __restrict__ blocksum) {
  __shared__ float wsum[4];
  const int wave = threadIdx.x >> 6, lane = threadIdx.x & 63;
  const int row = blockIdx.x * 4 + wave;
  const unsigned long long key = minkey[row];
  const int idx = (int)(unsigned int)(key & 0xFFFFFFFFULL);

  const float4 xv = *(const float4*)(x + (size_t)row * DIM + 4 * lane);
  const float4 ev = *(const float4*)(emb + (size_t)idx * DIM + 4 * lane);
  const float d0 = ev.x - xv.x, d1 = ev.y - xv.y, d2 = ev.z - xv.z, d3 = ev.w - xv.w;
  float4 o;
  o.x = xv.x + d0; o.y = xv.y + d1; o.z = xv.z + d2; o.w = xv.w + d3;
  *(float4*)(out + (size_t)row * DIM + 4 * lane) = o;

  float s = d0 * d0 + d1 * d1 + d2 * d2 + d3 * d3;
  #pragma unroll
  for (int off = 32; off; off >>= 1) s += __shfl_down(s, off);
  if (lane == 0) {
    wsum[wave] = s;
    out[OUT_IDX + row] = (float)idx;
  }
  __syncthreads();
  if (threadIdx.x == 0) blocksum[blockIdx.x] = wsum[0] + wsum[1] + wsum[2] + wsum[3];
}

__global__ void vq_finalize(const float* __restrict__ bs, float* __restrict__ out) {
  __shared__ float red[4];
  float s = 0.f;
  for (int i = threadIdx.x; i < N_ROWS / 4; i += 256) s += bs[i];
  #pragma unroll
  for (int off = 32; off; off >>= 1) s += __shfl_down(s, off);
  const int wave = threadIdx.x >> 6, lane = threadIdx.x & 63;
  if (lane == 0) red[wave] = s;
  __syncthreads();
  if (threadIdx.x == 0) {
    const float tot = red[0] + red[1] + red[2] + red[3];
    const float m = tot / 16777216.0f;      // mean((x_q - x)^2)
    out[OUT_LOSS] = m + 0.25f * m;          // codebook + BETA * commitment
  }
}

// ---------------------------------------------------------------------------
extern "C" void kernel_launch(void* const* d_in, const int* in_sizes, int n_in,
                              void* d_out, int out_size, void* d_ws, size_t ws_size,
                              hipStream_t stream) {
  const float* x = (const float*)d_in[0];
  const float* emb = (const float*)d_in[1];
  float* out = (float*)d_out;
  char* ws = (char*)d_ws;

  // ws layout: c[65536]f | e2[8192]f | minkey[65536]u64 | blocksum[16384]f  (~0.87 MB)
  float* c_g = (float*)(ws);
  float* e2_g = (float*)(ws + 262144);
  unsigned long long* minkey = (unsigned long long*)(ws + 294912);
  float* blocksum = (float*)(ws + 819200);

  hipMemsetAsync(minkey, 0xFF, (size_t)N_ROWS * 8, stream);  // u64 max for atomicMin

  sumsq_kernel<<<N_ROWS / 4, 256, 0, stream>>>(x, c_g);
  sumsq_kernel<<<NE / 4, 256, 0, stream>>>(emb, e2_g);

  vq_main<<<dim3(NE / 128, N_ROWS / 128), 256, 0, stream>>>(
      x, emb, c_g, e2_g, out + OUT_D, minkey);

  vq_epilogue<<<N_ROWS / 4, 256, 0, stream>>>(x, emb, minkey, out, blocksum);
  vq_finalize<<<1, 256, 0, stream>>>(blocksum, out);
}